// Round 1
// baseline (349.756 us; speedup 1.0000x reference)
//
#include <hip/hip_runtime.h>
#include <hip/hip_bf16.h>
#include <stdint.h>

#define SEQ 2048
#define BAT 32
#define EDIM 1024
#define MROWS (SEQ*BAT)   // 65536

typedef __bf16 bf16x8 __attribute__((ext_vector_type(8)));
typedef float f32x4 __attribute__((ext_vector_type(4)));
typedef unsigned short u16x8 __attribute__((ext_vector_type(8)));

typedef __attribute__((address_space(3))) unsigned int lds_uint;
typedef const __attribute__((address_space(1))) unsigned int glb_uint;

__device__ __forceinline__ void async16(void* lds, const void* g) {
  __builtin_amdgcn_global_load_lds((glb_uint*)g, (lds_uint*)lds, 16, 0, 0);
}

__device__ __forceinline__ unsigned short f2bf(float f) {
  unsigned u = __builtin_bit_cast(unsigned, f);
  u = (u + 0x7FFFu + ((u >> 16) & 1u)) >> 16;
  return (unsigned short)u;
}
__device__ __forceinline__ float bf2f(unsigned short h) {
  return __builtin_bit_cast(float, (unsigned)h << 16);
}

// ---------------- Kernel A: nv = g * v / ||v|| ----------------
__global__ void k_nv(const float* __restrict__ v, const float* __restrict__ g,
                     float* __restrict__ nv) {
  __shared__ float red[256];
  int t = threadIdx.x;
  float s = 0.f;
  for (int i = t; i < EDIM; i += 256) { float x = v[i]; s += x * x; }
  red[t] = s; __syncthreads();
  for (int o = 128; o > 0; o >>= 1) {
    if (t < o) red[t] += red[t + o];
    __syncthreads();
  }
  float scale = g[0] / sqrtf(red[0]);
  for (int i = t; i < EDIM; i += 256) nv[i] = v[i] * scale;
}

// ---------------- Kernel B: pqb[b][e] = query[b]·Wq[e] + bias[e] ----------------
__global__ void k_pqb(const float* __restrict__ query, const float* __restrict__ Wq,
                      const float* __restrict__ bias, float* __restrict__ pqb) {
  __shared__ float wq[1024];
  int e = blockIdx.x;
  int t = threadIdx.x;
  reinterpret_cast<float4*>(wq)[t] =
      reinterpret_cast<const float4*>(Wq + (size_t)e * EDIM)[t];
  __syncthreads();
  int w = t >> 6, lane = t & 63;
  float be = bias[e];
  for (int bb = 0; bb < 8; ++bb) {
    int b_ = w * 8 + bb;
    const float4* q4 = reinterpret_cast<const float4*>(query + (size_t)b_ * EDIM) + lane * 4;
    const float4* w4 = reinterpret_cast<const float4*>(wq) + lane * 4;
    float s = 0.f;
#pragma unroll
    for (int j = 0; j < 4; ++j) {
      float4 a = q4[j], c = w4[j];
      s += a.x * c.x + a.y * c.y + a.z * c.z + a.w * c.w;
    }
#pragma unroll
    for (int m = 32; m > 0; m >>= 1) s += __shfl_xor(s, m);
    if (lane == 0) pqb[(size_t)b_ * EDIM + e] = s + be;
  }
}

// ---------------- Kernel C: fp32 -> bf16 convert, 8 elems/thread ----------------
__global__ void k_cvt(const float* __restrict__ in, unsigned short* __restrict__ out,
                      long long n8) {
  long long i = (long long)blockIdx.x * blockDim.x + threadIdx.x;
  long long stride = (long long)gridDim.x * blockDim.x;
  for (; i < n8; i += stride) {
    const float4* p = reinterpret_cast<const float4*>(in + i * 8);
    float4 a = p[0], b = p[1];
    u16x8 r;
    r[0] = f2bf(a.x); r[1] = f2bf(a.y); r[2] = f2bf(a.z); r[3] = f2bf(a.w);
    r[4] = f2bf(b.x); r[5] = f2bf(b.y); r[6] = f2bf(b.z); r[7] = f2bf(b.w);
    *reinterpret_cast<u16x8*>(out + i * 8) = r;
  }
}

// ---------------- Kernel D: fused key-GEMM + nv·tanh(...) row reduce ----------------
// C[r][e] = sum_d value_bf[r][d] * Wv_bf[e][d]   (r = s*32+b)
// part[ni_blk][r] = sum_{e in 128-chunk} nv[e]*tanh(C[r][e] + pqb[b][e])
__global__ __launch_bounds__(256, 2) void k_gemm(
    const unsigned short* __restrict__ A,   // [MROWS][1024] bf16 bits
    const unsigned short* __restrict__ Bm,  // [1024][1024] bf16 bits
    const float* __restrict__ pqb,          // [32][1024]
    const float* __restrict__ nv,           // [1024]
    float* __restrict__ part)               // [8][MROWS]
{
  __shared__ unsigned short As[128 * 64];   // [row][k], 64 elems per row
  __shared__ unsigned short Bs[128 * 64];
  __shared__ float partLds[2][128];

  const int tid = threadIdx.x;
  const int lane = tid & 63;
  const int wave = tid >> 6;
  const int wm = wave >> 1, wn = wave & 1;
  const int ni_blk = blockIdx.x;            // 0..7
  const int mi_blk = blockIdx.y;            // 0..511
  const size_t m0 = (size_t)mi_blk * 128;
  const int n0 = ni_blk * 128;

  f32x4 acc[4][4];
#pragma unroll
  for (int i = 0; i < 4; ++i)
#pragma unroll
    for (int j = 0; j < 4; ++j) acc[i][j] = f32x4{0.f, 0.f, 0.f, 0.f};

  const int srow = tid >> 3;                // 0..31
  const int scol = (tid & 7) * 8;           // k element offset of 16B chunk

  for (int kt = 0; kt < 16; ++kt) {
    const int k0 = kt * 64;
#pragma unroll
    for (int i = 0; i < 4; ++i) {
      async16(&As[i * 2048 + tid * 8],
              A + (m0 + (size_t)(i * 32 + srow)) * 1024 + k0 + scol);
      async16(&Bs[i * 2048 + tid * 8],
              Bm + ((size_t)(n0 + i * 32 + srow)) * 1024 + k0 + scol);
    }
    __syncthreads();
#pragma unroll
    for (int kk = 0; kk < 2; ++kk) {
      bf16x8 af[4], bfr[4];
#pragma unroll
      for (int mi = 0; mi < 4; ++mi) {
        int row = wm * 64 + mi * 16 + (lane & 15);
        af[mi] = *reinterpret_cast<const bf16x8*>(&As[row * 64 + kk * 32 + ((lane >> 4) * 8)]);
      }
#pragma unroll
      for (int ni = 0; ni < 4; ++ni) {
        int row = wn * 64 + ni * 16 + (lane & 15);
        bfr[ni] = *reinterpret_cast<const bf16x8*>(&Bs[row * 64 + kk * 32 + ((lane >> 4) * 8)]);
      }
#pragma unroll
      for (int mi = 0; mi < 4; ++mi)
#pragma unroll
        for (int ni = 0; ni < 4; ++ni)
          acc[mi][ni] = __builtin_amdgcn_mfma_f32_16x16x32_bf16(af[mi], bfr[ni], acc[mi][ni], 0, 0, 0);
    }
    __syncthreads();
  }

  // Epilogue: C row = (lane>>4)*4+reg (+16*mi+64*wm), col = lane&15 (+16*ni+64*wn)
  const int cgrp = lane >> 4;
  const int ccol = lane & 15;
  float nve[4];
#pragma unroll
  for (int ni = 0; ni < 4; ++ni) nve[ni] = nv[n0 + wn * 64 + ni * 16 + ccol];

#pragma unroll
  for (int mi = 0; mi < 4; ++mi) {
#pragma unroll
    for (int r = 0; r < 4; ++r) {
      int rloc = wm * 64 + mi * 16 + cgrp * 4 + r;
      int b_ = rloc & 31;   // m0 is a multiple of 32
      const float* pq = pqb + (size_t)b_ * EDIM + n0 + wn * 64 + ccol;
      float s = 0.f;
#pragma unroll
      for (int ni = 0; ni < 4; ++ni) {
        float x = acc[mi][ni][r] + pq[ni * 16];
        s += nve[ni] * tanhf(x);
      }
      // reduce over the 16 lanes holding different cols of the same rows
      s += __shfl_xor(s, 1);
      s += __shfl_xor(s, 2);
      s += __shfl_xor(s, 4);
      s += __shfl_xor(s, 8);
      if (ccol == 0) partLds[wn][rloc] = s;
    }
  }
  __syncthreads();
  if (tid < 128)
    part[(size_t)ni_blk * MROWS + m0 + tid] = partLds[0][tid] + partLds[1][tid];
}

// ---------------- Kernel E: reduce 8 chunks + softmax over s ----------------
__global__ void k_softmax(const float* __restrict__ part,          // [8][MROWS]
                          const unsigned char* __restrict__ mask,  // [S][B]
                          float* __restrict__ scores,              // [MROWS]
                          float* __restrict__ out_attn)            // d_out + 32768
{
  int b_ = blockIdx.x;
  int t = threadIdx.x;
  __shared__ float red[256];
  float sc[8];
  float mx = -1e30f;
#pragma unroll
  for (int i = 0; i < 8; ++i) {
    int s_ = t + i * 256;
    size_t r = (size_t)s_ * BAT + b_;
    float v = 0.f;
#pragma unroll
    for (int c = 0; c < 8; ++c) v += part[(size_t)c * MROWS + r];
    if (mask[r]) v = -1e30f;
    sc[i] = v;
    mx = fmaxf(mx, v);
  }
  red[t] = mx; __syncthreads();
  for (int o = 128; o > 0; o >>= 1) {
    if (t < o) red[t] = fmaxf(red[t], red[t + o]);
    __syncthreads();
  }
  mx = red[0];
  __syncthreads();
  float sum = 0.f;
#pragma unroll
  for (int i = 0; i < 8; ++i) { sc[i] = expf(sc[i] - mx); sum += sc[i]; }
  red[t] = sum; __syncthreads();
  for (int o = 128; o > 0; o >>= 1) {
    if (t < o) red[t] += red[t + o];
    __syncthreads();
  }
  float inv = 1.f / red[0];
#pragma unroll
  for (int i = 0; i < 8; ++i) {
    int s_ = t + i * 256;
    size_t r = (size_t)s_ * BAT + b_;
    float w = sc[i] * inv;
    scores[r] = w;
    out_attn[r] = w;
    out_attn[MROWS + r] = w;
  }
}

// ---------------- Kernel F: context partials over s-chunks ----------------
__global__ void k_ctx(const unsigned short* __restrict__ Vb,  // [MROWS][1024] bf16
                      const float* __restrict__ scores,       // [MROWS]
                      float* __restrict__ pctx)               // [16][BAT][1024]
{
  int b_ = blockIdx.x;   // 0..31
  int sch = blockIdx.y;  // 0..7
  int t = threadIdx.x;
  int d8 = t & 127;
  int sr = t >> 7;
  float acc[8];
#pragma unroll
  for (int j = 0; j < 8; ++j) acc[j] = 0.f;
  int s0 = sch * 256;
  for (int i = 0; i < 128; ++i) {
    int s_ = s0 + i * 2 + sr;
    size_t r = (size_t)s_ * BAT + b_;
    float w = scores[r];
    u16x8 v = *reinterpret_cast<const u16x8*>(Vb + r * 1024 + d8 * 8);
#pragma unroll
    for (int j = 0; j < 8; ++j) acc[j] += w * bf2f(v[j]);
  }
  float* dst = pctx + ((size_t)(sch * 2 + sr) * BAT + b_) * 1024 + d8 * 8;
#pragma unroll
  for (int j = 0; j < 8; ++j) dst[j] = acc[j];
}

// ---------------- Kernel G: final context reduce ----------------
__global__ void k_ctx_reduce(const float* __restrict__ pctx, float* __restrict__ out) {
  int i = blockIdx.x * 256 + threadIdx.x;  // 0..32767
  float s = 0.f;
#pragma unroll
  for (int c = 0; c < 16; ++c) s += pctx[(size_t)c * 32768 + i];
  out[i] = s;
}

extern "C" void kernel_launch(void* const* d_in, const int* in_sizes, int n_in,
                              void* d_out, int out_size, void* d_ws, size_t ws_size,
                              hipStream_t stream) {
  const float* query = (const float*)d_in[0];
  const float* value = (const float*)d_in[1];
  const float* Wq    = (const float*)d_in[2];
  const float* Wv    = (const float*)d_in[3];
  const float* v     = (const float*)d_in[4];
  const float* bias  = (const float*)d_in[5];
  const float* g     = (const float*)d_in[6];
  const unsigned char* mask = (const unsigned char*)d_in[7];
  float* out = (float*)d_out;

  char* ws = (char*)d_ws;
  unsigned short* Vb  = (unsigned short*)ws;                        // 128 MB
  unsigned short* Wvb = (unsigned short*)(ws + (size_t)134217728);  // 2 MB
  float* pqb    = (float*)(ws + (size_t)134217728 + 2097152);       // 128 KB
  float* nv     = pqb + 32 * 1024;                                  // 4 KB
  float* part   = nv + 1024;                                        // 8*65536*4 = 2 MB
  float* scores = part + 8 * MROWS;                                 // 256 KB
  float* pctx   = scores + MROWS;                                   // 2 MB

  k_nv<<<1, 256, 0, stream>>>(v, g, nv);
  k_pqb<<<1024, 256, 0, stream>>>(query, Wq, bias, pqb);
  k_cvt<<<2048, 256, 0, stream>>>(value, Vb, (long long)(65536LL * 1024 / 8));
  k_cvt<<<512, 256, 0, stream>>>(Wv, Wvb, (long long)(1024LL * 1024 / 8));
  dim3 gg(8, 512);
  k_gemm<<<gg, 256, 0, stream>>>(Vb, Wvb, pqb, nv, part);
  k_softmax<<<32, 256, 0, stream>>>(part, mask, scores, out + 32768);
  dim3 gf(32, 8);
  k_ctx<<<gf, 256, 0, stream>>>(Vb, scores, pctx);
  k_ctx_reduce<<<128, 256, 0, stream>>>(pctx, out);
}

// Round 2
// 332.974 us; speedup vs baseline: 1.0504x; 1.0504x over previous
//
#include <hip/hip_runtime.h>
#include <hip/hip_bf16.h>
#include <stdint.h>

#define SEQ 2048
#define BAT 32
#define EDIM 1024
#define MROWS (SEQ*BAT)   // 65536

typedef __bf16 bf16x8 __attribute__((ext_vector_type(8)));
typedef float f32x4 __attribute__((ext_vector_type(4)));
typedef unsigned short u16x8 __attribute__((ext_vector_type(8)));

typedef __attribute__((address_space(3))) unsigned int lds_uint;
typedef const __attribute__((address_space(1))) unsigned int glb_uint;

__device__ __forceinline__ void async16(void* lds, const void* g) {
  __builtin_amdgcn_global_load_lds((glb_uint*)g, (lds_uint*)lds, 16, 0, 0);
}

__device__ __forceinline__ unsigned short f2bf(float f) {
  unsigned u = __builtin_bit_cast(unsigned, f);
  u = (u + 0x7FFFu + ((u >> 16) & 1u)) >> 16;
  return (unsigned short)u;
}
__device__ __forceinline__ float bf2f(unsigned short h) {
  return __builtin_bit_cast(float, (unsigned)h << 16);
}

// fast tanh: (e^{2x}-1)/(e^{2x}+1), clamped; ~7 VALU ops vs ~25 for ocml tanhf
__device__ __forceinline__ float fast_tanh(float x) {
  float xc = fminf(fmaxf(x, -9.f), 9.f);
  float e = __expf(2.f * xc);
  return (e - 1.f) * __builtin_amdgcn_rcpf(e + 1.f);
}

// ---------------- Kernel A: nv = g * v / ||v|| ----------------
__global__ void k_nv(const float* __restrict__ v, const float* __restrict__ g,
                     float* __restrict__ nv) {
  __shared__ float red[256];
  int t = threadIdx.x;
  float s = 0.f;
  for (int i = t; i < EDIM; i += 256) { float x = v[i]; s += x * x; }
  red[t] = s; __syncthreads();
  for (int o = 128; o > 0; o >>= 1) {
    if (t < o) red[t] += red[t + o];
    __syncthreads();
  }
  float scale = g[0] / sqrtf(red[0]);
  for (int i = t; i < EDIM; i += 256) nv[i] = v[i] * scale;
}

// ---------------- Kernel B: pqb[b][e] = query[b]·Wq[e] + bias[e] ----------------
__global__ void k_pqb(const float* __restrict__ query, const float* __restrict__ Wq,
                      const float* __restrict__ bias, float* __restrict__ pqb) {
  __shared__ float wq[1024];
  int e = blockIdx.x;
  int t = threadIdx.x;
  reinterpret_cast<float4*>(wq)[t] =
      reinterpret_cast<const float4*>(Wq + (size_t)e * EDIM)[t];
  __syncthreads();
  int w = t >> 6, lane = t & 63;
  float be = bias[e];
  for (int bb = 0; bb < 8; ++bb) {
    int b_ = w * 8 + bb;
    const float4* q4 = reinterpret_cast<const float4*>(query + (size_t)b_ * EDIM) + lane * 4;
    const float4* w4 = reinterpret_cast<const float4*>(wq) + lane * 4;
    float s = 0.f;
#pragma unroll
    for (int j = 0; j < 4; ++j) {
      float4 a = q4[j], c = w4[j];
      s += a.x * c.x + a.y * c.y + a.z * c.z + a.w * c.w;
    }
#pragma unroll
    for (int m = 32; m > 0; m >>= 1) s += __shfl_xor(s, m);
    if (lane == 0) pqb[(size_t)b_ * EDIM + e] = s + be;
  }
}

// ---------------- Kernel C: fp32 -> bf16 convert, 8 elems/thread ----------------
__global__ void k_cvt(const float* __restrict__ in, unsigned short* __restrict__ out,
                      long long n8) {
  long long i = (long long)blockIdx.x * blockDim.x + threadIdx.x;
  long long stride = (long long)gridDim.x * blockDim.x;
  for (; i < n8; i += stride) {
    const float4* p = reinterpret_cast<const float4*>(in + i * 8);
    float4 a = p[0], b = p[1];
    u16x8 r;
    r[0] = f2bf(a.x); r[1] = f2bf(a.y); r[2] = f2bf(a.z); r[3] = f2bf(a.w);
    r[4] = f2bf(b.x); r[5] = f2bf(b.y); r[6] = f2bf(b.z); r[7] = f2bf(b.w);
    *reinterpret_cast<u16x8*>(out + i * 8) = r;
  }
}

// ---------------- Kernel D: fused key-GEMM + nv·tanh(...) full row reduce ----------------
// Each block owns 128 rows (m0..m0+127) and loops over all 8 N-chunks of 128,
// so the A panel is read exactly once from HBM.
// raw[r] = sum_{e=0..1023} nv[e]*tanh(C[r][e] + pqb[b(r)][e]),  b(r)=r&31
__global__ __launch_bounds__(256, 2) void k_gemm(
    const unsigned short* __restrict__ A,   // [MROWS][1024] bf16 bits
    const unsigned short* __restrict__ Bm,  // [1024][1024] bf16 bits
    const float* __restrict__ pqb,          // [32][1024]
    const float* __restrict__ nv,           // [1024]
    float* __restrict__ raw)                // [MROWS]
{
  __shared__ unsigned short As[128 * 64];   // [row][k], 64 elems per row
  __shared__ unsigned short Bs[128 * 64];
  __shared__ float partLds[2][128];

  const int tid = threadIdx.x;
  const int lane = tid & 63;
  const int wave = tid >> 6;
  const int wm = wave >> 1, wn = wave & 1;
  const size_t m0 = (size_t)blockIdx.x * 128;

  const int srow = tid >> 3;                // 0..31
  const int scol = (tid & 7) * 8;           // k element offset of 16B chunk
  const int cgrp = lane >> 4;
  const int ccol = lane & 15;

  float rowacc[4][4];
#pragma unroll
  for (int i = 0; i < 4; ++i)
#pragma unroll
    for (int j = 0; j < 4; ++j) rowacc[i][j] = 0.f;

  for (int ni = 0; ni < 8; ++ni) {
    const int n0 = ni * 128;

    f32x4 acc[4][4];
#pragma unroll
    for (int i = 0; i < 4; ++i)
#pragma unroll
      for (int j = 0; j < 4; ++j) acc[i][j] = f32x4{0.f, 0.f, 0.f, 0.f};

    for (int kt = 0; kt < 16; ++kt) {
      const int k0 = kt * 64;
#pragma unroll
      for (int i = 0; i < 4; ++i) {
        async16(&As[i * 2048 + tid * 8],
                A + (m0 + (size_t)(i * 32 + srow)) * 1024 + k0 + scol);
        async16(&Bs[i * 2048 + tid * 8],
                Bm + ((size_t)(n0 + i * 32 + srow)) * 1024 + k0 + scol);
      }
      __syncthreads();
#pragma unroll
      for (int kk = 0; kk < 2; ++kk) {
        bf16x8 af[4], bfr[4];
#pragma unroll
        for (int mi = 0; mi < 4; ++mi) {
          int row = wm * 64 + mi * 16 + (lane & 15);
          af[mi] = *reinterpret_cast<const bf16x8*>(&As[row * 64 + kk * 32 + ((lane >> 4) * 8)]);
        }
#pragma unroll
        for (int nidx = 0; nidx < 4; ++nidx) {
          int row = wn * 64 + nidx * 16 + (lane & 15);
          bfr[nidx] = *reinterpret_cast<const bf16x8*>(&Bs[row * 64 + kk * 32 + ((lane >> 4) * 8)]);
        }
#pragma unroll
        for (int mi = 0; mi < 4; ++mi)
#pragma unroll
          for (int nidx = 0; nidx < 4; ++nidx)
            acc[mi][nidx] = __builtin_amdgcn_mfma_f32_16x16x32_bf16(af[mi], bfr[nidx], acc[mi][nidx], 0, 0, 0);
      }
      __syncthreads();
    }

    // Epilogue for this ni: C row = wm*64+mi*16+cgrp*4+r, col = n0+wn*64+nidx*16+ccol
    float nve[4];
#pragma unroll
    for (int nidx = 0; nidx < 4; ++nidx) nve[nidx] = nv[n0 + wn * 64 + nidx * 16 + ccol];

#pragma unroll
    for (int mi = 0; mi < 4; ++mi) {
#pragma unroll
      for (int r = 0; r < 4; ++r) {
        int b_ = (mi * 16 + cgrp * 4 + r) & 31;   // m0, wm*64 multiples of 32
        const float* pq = pqb + (size_t)b_ * EDIM + n0 + wn * 64 + ccol;
        float s = 0.f;
#pragma unroll
        for (int nidx = 0; nidx < 4; ++nidx) {
          float x = acc[mi][nidx][r] + pq[nidx * 16];
          s += nve[nidx] * fast_tanh(x);
        }
        rowacc[mi][r] += s;
      }
    }
  }

  // Final reduce over the 16 lanes (ccol) holding different col groups of same rows
#pragma unroll
  for (int mi = 0; mi < 4; ++mi) {
#pragma unroll
    for (int r = 0; r < 4; ++r) {
      float s = rowacc[mi][r];
      s += __shfl_xor(s, 1);
      s += __shfl_xor(s, 2);
      s += __shfl_xor(s, 4);
      s += __shfl_xor(s, 8);
      if (ccol == 0) partLds[wn][wm * 64 + mi * 16 + cgrp * 4 + r] = s;
    }
  }
  __syncthreads();
  if (tid < 128)
    raw[m0 + tid] = partLds[0][tid] + partLds[1][tid];
}

// ---------------- Kernel E: mask + softmax over s ----------------
__global__ void k_softmax(const float* __restrict__ raw,           // [MROWS]
                          const unsigned char* __restrict__ mask,  // [S][B]
                          float* __restrict__ scores,              // [MROWS]
                          float* __restrict__ out_attn)            // d_out + 32768
{
  int b_ = blockIdx.x;
  int t = threadIdx.x;
  __shared__ float red[256];
  float sc[8];
  float mx = -1e30f;
#pragma unroll
  for (int i = 0; i < 8; ++i) {
    int s_ = t + i * 256;
    size_t r = (size_t)s_ * BAT + b_;
    float v = raw[r];
    if (mask[r]) v = -1e30f;
    sc[i] = v;
    mx = fmaxf(mx, v);
  }
  red[t] = mx; __syncthreads();
  for (int o = 128; o > 0; o >>= 1) {
    if (t < o) red[t] = fmaxf(red[t], red[t + o]);
    __syncthreads();
  }
  mx = red[0];
  __syncthreads();
  float sum = 0.f;
#pragma unroll
  for (int i = 0; i < 8; ++i) { sc[i] = expf(sc[i] - mx); sum += sc[i]; }
  red[t] = sum; __syncthreads();
  for (int o = 128; o > 0; o >>= 1) {
    if (t < o) red[t] += red[t + o];
    __syncthreads();
  }
  float inv = 1.f / red[0];
#pragma unroll
  for (int i = 0; i < 8; ++i) {
    int s_ = t + i * 256;
    size_t r = (size_t)s_ * BAT + b_;
    float w = sc[i] * inv;
    scores[r] = w;
    out_attn[r] = w;
    out_attn[MROWS + r] = w;
  }
}

// ---------------- Kernel F: context partials over s-chunks ----------------
__global__ void k_ctx(const unsigned short* __restrict__ Vb,  // [MROWS][1024] bf16
                      const float* __restrict__ scores,       // [MROWS]
                      float* __restrict__ pctx)               // [16][BAT][1024]
{
  int b_ = blockIdx.x;   // 0..31
  int sch = blockIdx.y;  // 0..7
  int t = threadIdx.x;
  int d8 = t & 127;
  int sr = t >> 7;
  float acc[8];
#pragma unroll
  for (int j = 0; j < 8; ++j) acc[j] = 0.f;
  int s0 = sch * 256;
  for (int i = 0; i < 128; ++i) {
    int s_ = s0 + i * 2 + sr;
    size_t r = (size_t)s_ * BAT + b_;
    float w = scores[r];
    u16x8 v = *reinterpret_cast<const u16x8*>(Vb + r * 1024 + d8 * 8);
#pragma unroll
    for (int j = 0; j < 8; ++j) acc[j] += w * bf2f(v[j]);
  }
  float* dst = pctx + ((size_t)(sch * 2 + sr) * BAT + b_) * 1024 + d8 * 8;
#pragma unroll
  for (int j = 0; j < 8; ++j) dst[j] = acc[j];
}

// ---------------- Kernel G: final context reduce ----------------
__global__ void k_ctx_reduce(const float* __restrict__ pctx, float* __restrict__ out) {
  int i = blockIdx.x * 256 + threadIdx.x;  // 0..32767
  float s = 0.f;
#pragma unroll
  for (int c = 0; c < 16; ++c) s += pctx[(size_t)c * 32768 + i];
  out[i] = s;
}

extern "C" void kernel_launch(void* const* d_in, const int* in_sizes, int n_in,
                              void* d_out, int out_size, void* d_ws, size_t ws_size,
                              hipStream_t stream) {
  const float* query = (const float*)d_in[0];
  const float* value = (const float*)d_in[1];
  const float* Wq    = (const float*)d_in[2];
  const float* Wv    = (const float*)d_in[3];
  const float* v     = (const float*)d_in[4];
  const float* bias  = (const float*)d_in[5];
  const float* g     = (const float*)d_in[6];
  const unsigned char* mask = (const unsigned char*)d_in[7];
  float* out = (float*)d_out;

  char* ws = (char*)d_ws;
  unsigned short* Vb  = (unsigned short*)ws;                        // 128 MB
  unsigned short* Wvb = (unsigned short*)(ws + (size_t)134217728);  // 2 MB
  float* pqb    = (float*)(ws + (size_t)134217728 + 2097152);       // 128 KB
  float* nv     = pqb + 32 * 1024;                                  // 4 KB
  float* raw    = nv + 1024;                                        // 256 KB
  float* scores = raw + MROWS;                                      // 256 KB
  float* pctx   = scores + MROWS;                                   // 2 MB

  k_nv<<<1, 256, 0, stream>>>(v, g, nv);
  k_pqb<<<1024, 256, 0, stream>>>(query, Wq, bias, pqb);
  k_cvt<<<2048, 256, 0, stream>>>(value, Vb, (long long)(65536LL * 1024 / 8));
  k_cvt<<<512, 256, 0, stream>>>(Wv, Wvb, (long long)(1024LL * 1024 / 8));
  k_gemm<<<512, 256, 0, stream>>>(Vb, Wvb, pqb, nv, raw);
  k_softmax<<<32, 256, 0, stream>>>(raw, mask, scores, out + 32768);
  dim3 gf(32, 8);
  k_ctx<<<gf, 256, 0, stream>>>(Vb, scores, pctx);
  k_ctx_reduce<<<128, 256, 0, stream>>>(pctx, out);
}

// Round 3
// 312.931 us; speedup vs baseline: 1.1177x; 1.0640x over previous
//
#include <hip/hip_runtime.h>
#include <hip/hip_bf16.h>
#include <stdint.h>

#define SEQ 2048
#define BAT 32
#define EDIM 1024
#define MROWS (SEQ*BAT)   // 65536

typedef __bf16 bf16x8 __attribute__((ext_vector_type(8)));
typedef float f32x4 __attribute__((ext_vector_type(4)));
typedef unsigned short u16x8 __attribute__((ext_vector_type(8)));

typedef __attribute__((address_space(3))) unsigned int lds_uint;
typedef const __attribute__((address_space(1))) unsigned int glb_uint;

__device__ __forceinline__ void async16(void* lds, const void* g) {
  __builtin_amdgcn_global_load_lds((glb_uint*)g, (lds_uint*)lds, 16, 0, 0);
}

__device__ __forceinline__ unsigned short f2bf(float f) {
  unsigned u = __builtin_bit_cast(unsigned, f);
  u = (u + 0x7FFFu + ((u >> 16) & 1u)) >> 16;
  return (unsigned short)u;
}
__device__ __forceinline__ float bf2f(unsigned short h) {
  return __builtin_bit_cast(float, (unsigned)h << 16);
}

// fast tanh: (e^{2x}-1)/(e^{2x}+1), clamped; ~7 VALU ops vs ~25 for ocml tanhf
__device__ __forceinline__ float fast_tanh(float x) {
  float xc = fminf(fmaxf(x, -9.f), 9.f);
  float e = __expf(2.f * xc);
  return (e - 1.f) * __builtin_amdgcn_rcpf(e + 1.f);
}

// ---------------- Kernel A: nv = g * v / ||v|| ----------------
__global__ void k_nv(const float* __restrict__ v, const float* __restrict__ g,
                     float* __restrict__ nv) {
  __shared__ float red[256];
  int t = threadIdx.x;
  float s = 0.f;
  for (int i = t; i < EDIM; i += 256) { float x = v[i]; s += x * x; }
  red[t] = s; __syncthreads();
  for (int o = 128; o > 0; o >>= 1) {
    if (t < o) red[t] += red[t + o];
    __syncthreads();
  }
  float scale = g[0] / sqrtf(red[0]);
  for (int i = t; i < EDIM; i += 256) nv[i] = v[i] * scale;
}

// ---------------- Kernel B: pqb[b][e] = query[b]·Wq[e] + bias[e] ----------------
__global__ void k_pqb(const float* __restrict__ query, const float* __restrict__ Wq,
                      const float* __restrict__ bias, float* __restrict__ pqb) {
  __shared__ float wq[1024];
  int e = blockIdx.x;
  int t = threadIdx.x;
  reinterpret_cast<float4*>(wq)[t] =
      reinterpret_cast<const float4*>(Wq + (size_t)e * EDIM)[t];
  __syncthreads();
  int w = t >> 6, lane = t & 63;
  float be = bias[e];
  for (int bb = 0; bb < 8; ++bb) {
    int b_ = w * 8 + bb;
    const float4* q4 = reinterpret_cast<const float4*>(query + (size_t)b_ * EDIM) + lane * 4;
    const float4* w4 = reinterpret_cast<const float4*>(wq) + lane * 4;
    float s = 0.f;
#pragma unroll
    for (int j = 0; j < 4; ++j) {
      float4 a = q4[j], c = w4[j];
      s += a.x * c.x + a.y * c.y + a.z * c.z + a.w * c.w;
    }
#pragma unroll
    for (int m = 32; m > 0; m >>= 1) s += __shfl_xor(s, m);
    if (lane == 0) pqb[(size_t)b_ * EDIM + e] = s + be;
  }
}

// ---------------- Kernel C: fp32 -> bf16 convert, 8 elems/thread ----------------
__global__ void k_cvt(const float* __restrict__ in, unsigned short* __restrict__ out,
                      long long n8) {
  long long i = (long long)blockIdx.x * blockDim.x + threadIdx.x;
  long long stride = (long long)gridDim.x * blockDim.x;
  for (; i < n8; i += stride) {
    const float4* p = reinterpret_cast<const float4*>(in + i * 8);
    float4 a = p[0], b = p[1];
    u16x8 r;
    r[0] = f2bf(a.x); r[1] = f2bf(a.y); r[2] = f2bf(a.z); r[3] = f2bf(a.w);
    r[4] = f2bf(b.x); r[5] = f2bf(b.y); r[6] = f2bf(b.z); r[7] = f2bf(b.w);
    *reinterpret_cast<u16x8*>(out + i * 8) = r;
  }
}

// ---------------- Kernel D: fused key-GEMM + nv·tanh(...) chunk reduce ----------------
// One (mi, ni) 128x128 tile per block. T1 chunked XCD swizzle: the 8 ni-blocks
// sharing an A-panel run concurrently on the SAME XCD -> A fetched once into
// that XCD's L2, 7 L2 hits. Per-XCD window: 8 panels x 256KB + B 2MB ~= L2.
__global__ __launch_bounds__(256, 4) void k_gemm(
    const unsigned short* __restrict__ A,   // [MROWS][1024] bf16 bits
    const unsigned short* __restrict__ Bm,  // [1024][1024] bf16 bits
    const float* __restrict__ pqb,          // [32][1024]
    const float* __restrict__ nv,           // [1024]
    float* __restrict__ part)               // [8][MROWS]
{
  __shared__ unsigned short As[128 * 64];   // [row][k], 64 elems per row
  __shared__ unsigned short Bs[128 * 64];
  __shared__ float partLds[2][128];

  const int tid = threadIdx.x;
  const int lane = tid & 63;
  const int wave = tid >> 6;
  const int wm = wave >> 1, wn = wave & 1;

  // XCD-chunked mapping: round-robin dispatch puts bid%8 on XCD bid%8.
  const int bid = blockIdx.x;               // 0..4095
  const int x = bid & 7;                    // XCD
  const int j = bid >> 3;                   // 0..511
  const int mi_blk = x * 64 + (j >> 3);     // 64 consecutive panels per XCD
  const int ni_blk = j & 7;
  const size_t m0 = (size_t)mi_blk * 128;
  const int n0 = ni_blk * 128;

  f32x4 acc[4][4];
#pragma unroll
  for (int i = 0; i < 4; ++i)
#pragma unroll
    for (int jj = 0; jj < 4; ++jj) acc[i][jj] = f32x4{0.f, 0.f, 0.f, 0.f};

  const int srow = tid >> 3;                // 0..31
  const int scol = (tid & 7) * 8;           // k element offset of 16B chunk

  for (int kt = 0; kt < 16; ++kt) {
    const int k0 = kt * 64;
#pragma unroll
    for (int i = 0; i < 4; ++i) {
      async16(&As[i * 2048 + tid * 8],
              A + (m0 + (size_t)(i * 32 + srow)) * 1024 + k0 + scol);
      async16(&Bs[i * 2048 + tid * 8],
              Bm + ((size_t)(n0 + i * 32 + srow)) * 1024 + k0 + scol);
    }
    __syncthreads();
#pragma unroll
    for (int kk = 0; kk < 2; ++kk) {
      bf16x8 af[4], bfr[4];
#pragma unroll
      for (int mi = 0; mi < 4; ++mi) {
        int row = wm * 64 + mi * 16 + (lane & 15);
        af[mi] = *reinterpret_cast<const bf16x8*>(&As[row * 64 + kk * 32 + ((lane >> 4) * 8)]);
      }
#pragma unroll
      for (int nidx = 0; nidx < 4; ++nidx) {
        int row = wn * 64 + nidx * 16 + (lane & 15);
        bfr[nidx] = *reinterpret_cast<const bf16x8*>(&Bs[row * 64 + kk * 32 + ((lane >> 4) * 8)]);
      }
#pragma unroll
      for (int mi = 0; mi < 4; ++mi)
#pragma unroll
        for (int nidx = 0; nidx < 4; ++nidx)
          acc[mi][nidx] = __builtin_amdgcn_mfma_f32_16x16x32_bf16(af[mi], bfr[nidx], acc[mi][nidx], 0, 0, 0);
    }
    __syncthreads();
  }

  // Epilogue: C row = wm*64+mi*16+(lane>>4)*4+r, col = n0+wn*64+nidx*16+(lane&15)
  const int cgrp = lane >> 4;
  const int ccol = lane & 15;
  float nve[4];
#pragma unroll
  for (int nidx = 0; nidx < 4; ++nidx) nve[nidx] = nv[n0 + wn * 64 + nidx * 16 + ccol];

#pragma unroll
  for (int mi = 0; mi < 4; ++mi) {
#pragma unroll
    for (int r = 0; r < 4; ++r) {
      int rloc = wm * 64 + mi * 16 + cgrp * 4 + r;
      int b_ = rloc & 31;   // m0 is a multiple of 32
      const float* pq = pqb + (size_t)b_ * EDIM + n0 + wn * 64 + ccol;
      float s = 0.f;
#pragma unroll
      for (int nidx = 0; nidx < 4; ++nidx) {
        float xin = acc[mi][nidx][r] + pq[nidx * 16];
        s += nve[nidx] * fast_tanh(xin);
      }
      s += __shfl_xor(s, 1);
      s += __shfl_xor(s, 2);
      s += __shfl_xor(s, 4);
      s += __shfl_xor(s, 8);
      if (ccol == 0) partLds[wn][rloc] = s;
    }
  }
  __syncthreads();
  if (tid < 128)
    part[(size_t)ni_blk * MROWS + m0 + tid] = partLds[0][tid] + partLds[1][tid];
}

// ---------------- Kernel E: reduce 8 chunks + mask + softmax over s ----------------
__global__ void k_softmax(const float* __restrict__ part,          // [8][MROWS]
                          const unsigned char* __restrict__ mask,  // [S][B]
                          float* __restrict__ scores,              // [MROWS]
                          float* __restrict__ out_attn)            // d_out + 32768
{
  int b_ = blockIdx.x;
  int t = threadIdx.x;
  __shared__ float red[256];
  float sc[8];
  float mx = -1e30f;
#pragma unroll
  for (int i = 0; i < 8; ++i) {
    int s_ = t + i * 256;
    size_t r = (size_t)s_ * BAT + b_;
    float v = 0.f;
#pragma unroll
    for (int c = 0; c < 8; ++c) v += part[(size_t)c * MROWS + r];
    if (mask[r]) v = -1e30f;
    sc[i] = v;
    mx = fmaxf(mx, v);
  }
  red[t] = mx; __syncthreads();
  for (int o = 128; o > 0; o >>= 1) {
    if (t < o) red[t] = fmaxf(red[t], red[t + o]);
    __syncthreads();
  }
  mx = red[0];
  __syncthreads();
  float sum = 0.f;
#pragma unroll
  for (int i = 0; i < 8; ++i) { sc[i] = expf(sc[i] - mx); sum += sc[i]; }
  red[t] = sum; __syncthreads();
  for (int o = 128; o > 0; o >>= 1) {
    if (t < o) red[t] += red[t + o];
    __syncthreads();
  }
  float inv = 1.f / red[0];
#pragma unroll
  for (int i = 0; i < 8; ++i) {
    int s_ = t + i * 256;
    size_t r = (size_t)s_ * BAT + b_;
    float w = sc[i] * inv;
    scores[r] = w;
    out_attn[r] = w;
    out_attn[MROWS + r] = w;
  }
}

// ---------------- Kernel F: context partials over s-chunks ----------------
__global__ void k_ctx(const unsigned short* __restrict__ Vb,  // [MROWS][1024] bf16
                      const float* __restrict__ scores,       // [MROWS]
                      float* __restrict__ pctx)               // [16][BAT][1024]
{
  int b_ = blockIdx.x;   // 0..31
  int sch = blockIdx.y;  // 0..7
  int t = threadIdx.x;
  int d8 = t & 127;
  int sr = t >> 7;
  float acc[8];
#pragma unroll
  for (int j = 0; j < 8; ++j) acc[j] = 0.f;
  int s0 = sch * 256;
  for (int i = 0; i < 128; ++i) {
    int s_ = s0 + i * 2 + sr;
    size_t r = (size_t)s_ * BAT + b_;
    float w = scores[r];
    u16x8 v = *reinterpret_cast<const u16x8*>(Vb + r * 1024 + d8 * 8);
#pragma unroll
    for (int j = 0; j < 8; ++j) acc[j] += w * bf2f(v[j]);
  }
  float* dst = pctx + ((size_t)(sch * 2 + sr) * BAT + b_) * 1024 + d8 * 8;
#pragma unroll
  for (int j = 0; j < 8; ++j) dst[j] = acc[j];
}

// ---------------- Kernel G: final context reduce ----------------
__global__ void k_ctx_reduce(const float* __restrict__ pctx, float* __restrict__ out) {
  int i = blockIdx.x * 256 + threadIdx.x;  // 0..32767
  float s = 0.f;
#pragma unroll
  for (int c = 0; c < 16; ++c) s += pctx[(size_t)c * 32768 + i];
  out[i] = s;
}

extern "C" void kernel_launch(void* const* d_in, const int* in_sizes, int n_in,
                              void* d_out, int out_size, void* d_ws, size_t ws_size,
                              hipStream_t stream) {
  const float* query = (const float*)d_in[0];
  const float* value = (const float*)d_in[1];
  const float* Wq    = (const float*)d_in[2];
  const float* Wv    = (const float*)d_in[3];
  const float* v     = (const float*)d_in[4];
  const float* bias  = (const float*)d_in[5];
  const float* g     = (const float*)d_in[6];
  const unsigned char* mask = (const unsigned char*)d_in[7];
  float* out = (float*)d_out;

  char* ws = (char*)d_ws;
  unsigned short* Vb  = (unsigned short*)ws;                        // 128 MB
  unsigned short* Wvb = (unsigned short*)(ws + (size_t)134217728);  // 2 MB
  float* pqb    = (float*)(ws + (size_t)134217728 + 2097152);       // 128 KB
  float* nv     = pqb + 32 * 1024;                                  // 4 KB
  float* part   = nv + 1024;                                        // 8*65536*4 = 2 MB
  float* scores = part + 8 * MROWS;                                 // 256 KB
  float* pctx   = scores + MROWS;                                   // 2 MB

  k_nv<<<1, 256, 0, stream>>>(v, g, nv);
  k_pqb<<<1024, 256, 0, stream>>>(query, Wq, bias, pqb);
  k_cvt<<<2048, 256, 0, stream>>>(value, Vb, (long long)(65536LL * 1024 / 8));
  k_cvt<<<512, 256, 0, stream>>>(Wv, Wvb, (long long)(1024LL * 1024 / 8));
  k_gemm<<<4096, 256, 0, stream>>>(Vb, Wvb, pqb, nv, part);
  k_softmax<<<32, 256, 0, stream>>>(part, mask, scores, out + 32768);
  dim3 gf(32, 8);
  k_ctx<<<gf, 256, 0, stream>>>(Vb, scores, pctx);
  k_ctx_reduce<<<128, 256, 0, stream>>>(pctx, out);
}

// Round 4
// 273.716 us; speedup vs baseline: 1.2778x; 1.1433x over previous
//
#include <hip/hip_runtime.h>
#include <hip/hip_bf16.h>
#include <stdint.h>

#define SEQ 2048
#define BAT 32
#define EDIM 1024
#define MROWS (SEQ*BAT)   // 65536

typedef __bf16 bf16x8 __attribute__((ext_vector_type(8)));
typedef float f32x4 __attribute__((ext_vector_type(4)));
typedef unsigned short u16x8 __attribute__((ext_vector_type(8)));

typedef __attribute__((address_space(3))) unsigned int lds_uint;
typedef const __attribute__((address_space(1))) unsigned int glb_uint;

__device__ __forceinline__ void async16(void* lds, const void* g) {
  __builtin_amdgcn_global_load_lds((glb_uint*)g, (lds_uint*)lds, 16, 0, 0);
}

__device__ __forceinline__ unsigned short f2bf(float f) {
  unsigned u = __builtin_bit_cast(unsigned, f);
  u = (u + 0x7FFFu + ((u >> 16) & 1u)) >> 16;
  return (unsigned short)u;
}
__device__ __forceinline__ float bf2f(unsigned short h) {
  return __builtin_bit_cast(float, (unsigned)h << 16);
}

// fast tanh: (e^{2x}-1)/(e^{2x}+1), clamped; ~7 VALU ops vs ~25 for ocml tanhf
__device__ __forceinline__ float fast_tanh(float x) {
  float xc = fminf(fmaxf(x, -9.f), 9.f);
  float e = __expf(2.f * xc);
  return (e - 1.f) * __builtin_amdgcn_rcpf(e + 1.f);
}

// ---------------- Kernel A: nv = g * v / ||v|| ----------------
__global__ void k_nv(const float* __restrict__ v, const float* __restrict__ g,
                     float* __restrict__ nv) {
  __shared__ float red[256];
  int t = threadIdx.x;
  float s = 0.f;
  for (int i = t; i < EDIM; i += 256) { float x = v[i]; s += x * x; }
  red[t] = s; __syncthreads();
  for (int o = 128; o > 0; o >>= 1) {
    if (t < o) red[t] += red[t + o];
    __syncthreads();
  }
  float scale = g[0] / sqrtf(red[0]);
  for (int i = t; i < EDIM; i += 256) nv[i] = v[i] * scale;
}

// ---------------- Kernel B: pqb[b][e] = query[b]·Wq[e] + bias[e] ----------------
__global__ void k_pqb(const float* __restrict__ query, const float* __restrict__ Wq,
                      const float* __restrict__ bias, float* __restrict__ pqb) {
  __shared__ float wq[1024];
  int e = blockIdx.x;
  int t = threadIdx.x;
  reinterpret_cast<float4*>(wq)[t] =
      reinterpret_cast<const float4*>(Wq + (size_t)e * EDIM)[t];
  __syncthreads();
  int w = t >> 6, lane = t & 63;
  float be = bias[e];
  for (int bb = 0; bb < 8; ++bb) {
    int b_ = w * 8 + bb;
    const float4* q4 = reinterpret_cast<const float4*>(query + (size_t)b_ * EDIM) + lane * 4;
    const float4* w4 = reinterpret_cast<const float4*>(wq) + lane * 4;
    float s = 0.f;
#pragma unroll
    for (int j = 0; j < 4; ++j) {
      float4 a = q4[j], c = w4[j];
      s += a.x * c.x + a.y * c.y + a.z * c.z + a.w * c.w;
    }
#pragma unroll
    for (int m = 32; m > 0; m >>= 1) s += __shfl_xor(s, m);
    if (lane == 0) pqb[(size_t)b_ * EDIM + e] = s + be;
  }
}

// ---------------- Kernel C: fp32 -> bf16 convert, 8 elems/thread ----------------
__global__ void k_cvt(const float* __restrict__ in, unsigned short* __restrict__ out,
                      long long n8) {
  long long i = (long long)blockIdx.x * blockDim.x + threadIdx.x;
  long long stride = (long long)gridDim.x * blockDim.x;
  for (; i < n8; i += stride) {
    const float4* p = reinterpret_cast<const float4*>(in + i * 8);
    float4 a = p[0], b = p[1];
    u16x8 r;
    r[0] = f2bf(a.x); r[1] = f2bf(a.y); r[2] = f2bf(a.z); r[3] = f2bf(a.w);
    r[4] = f2bf(b.x); r[5] = f2bf(b.y); r[6] = f2bf(b.z); r[7] = f2bf(b.w);
    *reinterpret_cast<u16x8*>(out + i * 8) = r;
  }
}

// ---------------- Kernel D: 256x256-tile pipelined GEMM + nv·tanh reduce ----------------
// 8 waves (2 M x 4 N), BK=64, double-buffered 128 KiB LDS.
// Prefetch for tile t+1 issued at iteration top -> overlaps the 64-MFMA phase;
// the single __syncthreads per K-tile drains loads that are ~2400 cycles old.
// T2 XOR swizzle on 16B chunks (inverse-swizzled GLOBAL source, linear LDS dest,
// swizzled ds_read) kills the 16-way bank conflict of the 128B-stride reads.
__global__ __launch_bounds__(512, 1) void k_gemm(
    const unsigned short* __restrict__ A,   // [MROWS][1024] bf16 bits
    const unsigned short* __restrict__ Bm,  // [1024][1024] bf16 bits
    const float* __restrict__ pqb,          // [32][1024]
    const float* __restrict__ nv,           // [1024]
    float* __restrict__ part)               // [4][MROWS]
{
  // slot s: A at s*65536, B at s*65536+32768; partLds at 131072
  __shared__ char smem[2 * 65536 + 4 * 256 * 4];

  const int tid = threadIdx.x;
  const int lane = tid & 63;
  const int wid = tid >> 6;
  const int wm = wid >> 2;                  // 0..1
  const int wn = wid & 3;                   // 0..3

  // XCD-chunked mapping: 4 ni-siblings of one A-panel adjacent on one XCD.
  const int bid = blockIdx.x;               // 0..1023
  const int x = bid & 7;                    // XCD
  const int j = bid >> 3;                   // 0..127
  const int mi_blk = x * 32 + (j >> 2);
  const int ni_blk = j & 3;
  const size_t m0 = (size_t)mi_blk * 256;
  const int n0 = ni_blk * 256;

  float* partLds = (float*)(smem + 131072);

  f32x4 acc[8][4];
#pragma unroll
  for (int i = 0; i < 8; ++i)
#pragma unroll
    for (int jj = 0; jj < 4; ++jj) acc[i][jj] = f32x4{0.f, 0.f, 0.f, 0.f};

  // per-lane swizzled chunk columns for ds_read (row&7 == lane&7 at all frag rows)
  const int cs0 = (lane >> 4) ^ (lane & 7);   // kk=0
  const int cs1 = cs0 ^ 4;                    // kk=1
  const int rA = lane & 15;

  // staging: chunk = i*512+tid -> (row=chunk>>3, c=chunk&7); LDS linear dest,
  // global source column inverse-swizzled: csrc = c ^ (row&7)
  auto stageA = [&](int slot, int k0) {
#pragma unroll
    for (int i = 0; i < 4; ++i) {
      int chunk = i * 512 + tid;
      int row = chunk >> 3;
      int csrc = (chunk & 7) ^ (row & 7);
      async16(smem + slot * 65536 + chunk * 16,
              A + (m0 + (size_t)row) * 1024 + k0 + csrc * 8);
    }
  };
  auto stageB = [&](int slot, int k0) {
#pragma unroll
    for (int i = 0; i < 4; ++i) {
      int chunk = i * 512 + tid;
      int row = chunk >> 3;
      int csrc = (chunk & 7) ^ (row & 7);
      async16(smem + slot * 65536 + 32768 + chunk * 16,
              Bm + (size_t)(n0 + row) * 1024 + k0 + csrc * 8);
    }
  };

  stageA(0, 0);
  stageB(0, 0);
  __syncthreads();   // drain prologue loads

#pragma unroll 1
  for (int t = 0; t < 16; ++t) {
    char* cb = smem + (t & 1) * 65536;
    const int nslot = (t + 1) & 1;
    const int nk0 = (t + 1) * 64;
    const bool pf = (t + 1) < 16;

    if (pf) stageA(nslot, nk0);   // issue early: flies under the MFMA phase

#pragma unroll
    for (int kk = 0; kk < 2; ++kk) {
      const int cs = kk ? cs1 : cs0;
      bf16x8 af[8], bf[4];
#pragma unroll
      for (int mi = 0; mi < 8; ++mi)
        af[mi] = *reinterpret_cast<const bf16x8*>(
            cb + (wm * 128 + mi * 16 + rA) * 128 + cs * 16);
#pragma unroll
      for (int nj = 0; nj < 2; ++nj)
        bf[nj] = *reinterpret_cast<const bf16x8*>(
            cb + 32768 + (wn * 64 + nj * 16 + rA) * 128 + cs * 16);

      __builtin_amdgcn_s_setprio(1);
#pragma unroll
      for (int mi = 0; mi < 8; ++mi)
#pragma unroll
        for (int nj = 0; nj < 2; ++nj)
          acc[mi][nj] = __builtin_amdgcn_mfma_f32_16x16x32_bf16(af[mi], bf[nj], acc[mi][nj], 0, 0, 0);
      __builtin_amdgcn_s_setprio(0);

      if (kk == 0 && pf) stageB(nslot, nk0);

#pragma unroll
      for (int nj = 2; nj < 4; ++nj)
        bf[nj] = *reinterpret_cast<const bf16x8*>(
            cb + 32768 + (wn * 64 + nj * 16 + rA) * 128 + cs * 16);

      __builtin_amdgcn_s_setprio(1);
#pragma unroll
      for (int mi = 0; mi < 8; ++mi)
#pragma unroll
        for (int nj = 2; nj < 4; ++nj)
          acc[mi][nj] = __builtin_amdgcn_mfma_f32_16x16x32_bf16(af[mi], bf[nj], acc[mi][nj], 0, 0, 0);
      __builtin_amdgcn_s_setprio(0);
    }
    __syncthreads();  // vmcnt(0)+barrier: tile t+1 resident, buffers swappable
  }

  // Epilogue: C row = wm*128+mi*16+(lane>>4)*4+r, col = n0+wn*64+nj*16+(lane&15)
  const int cgrp = lane >> 4;
  const int ccol = lane & 15;
  float nve[4];
#pragma unroll
  for (int nj = 0; nj < 4; ++nj) nve[nj] = nv[n0 + wn * 64 + nj * 16 + ccol];

#pragma unroll
  for (int mi = 0; mi < 8; ++mi) {
#pragma unroll
    for (int r = 0; r < 4; ++r) {
      int rloc = wm * 128 + mi * 16 + cgrp * 4 + r;
      int b_ = rloc & 31;   // m0 is a multiple of 256
      const float* pq = pqb + (size_t)b_ * EDIM + n0 + wn * 64 + ccol;
      float s = 0.f;
#pragma unroll
      for (int nj = 0; nj < 4; ++nj)
        s += nve[nj] * fast_tanh(acc[mi][nj][r] + pq[nj * 16]);
      s += __shfl_xor(s, 1);
      s += __shfl_xor(s, 2);
      s += __shfl_xor(s, 4);
      s += __shfl_xor(s, 8);
      if (ccol == 0) partLds[wn * 256 + rloc] = s;
    }
  }
  __syncthreads();
  if (tid < 256)
    part[(size_t)ni_blk * MROWS + m0 + tid] =
        partLds[tid] + partLds[256 + tid] + partLds[512 + tid] + partLds[768 + tid];
}

// ---------------- Kernel E: reduce 4 chunks + mask + softmax over s ----------------
__global__ void k_softmax(const float* __restrict__ part,          // [4][MROWS]
                          const unsigned char* __restrict__ mask,  // [S][B]
                          float* __restrict__ scores,              // [MROWS]
                          float* __restrict__ out_attn)            // d_out + 32768
{
  int b_ = blockIdx.x;
  int t = threadIdx.x;
  __shared__ float red[256];
  float sc[8];
  float mx = -1e30f;
#pragma unroll
  for (int i = 0; i < 8; ++i) {
    int s_ = t + i * 256;
    size_t r = (size_t)s_ * BAT + b_;
    float v = 0.f;
#pragma unroll
    for (int c = 0; c < 4; ++c) v += part[(size_t)c * MROWS + r];
    if (mask[r]) v = -1e30f;
    sc[i] = v;
    mx = fmaxf(mx, v);
  }
  red[t] = mx; __syncthreads();
  for (int o = 128; o > 0; o >>= 1) {
    if (t < o) red[t] = fmaxf(red[t], red[t + o]);
    __syncthreads();
  }
  mx = red[0];
  __syncthreads();
  float sum = 0.f;
#pragma unroll
  for (int i = 0; i < 8; ++i) { sc[i] = expf(sc[i] - mx); sum += sc[i]; }
  red[t] = sum; __syncthreads();
  for (int o = 128; o > 0; o >>= 1) {
    if (t < o) red[t] += red[t + o];
    __syncthreads();
  }
  float inv = 1.f / red[0];
#pragma unroll
  for (int i = 0; i < 8; ++i) {
    int s_ = t + i * 256;
    size_t r = (size_t)s_ * BAT + b_;
    float w = sc[i] * inv;
    scores[r] = w;
    out_attn[r] = w;
    out_attn[MROWS + r] = w;
  }
}

// ---------------- Kernel F: context partials over s-chunks ----------------
__global__ void k_ctx(const unsigned short* __restrict__ Vb,  // [MROWS][1024] bf16
                      const float* __restrict__ scores,       // [MROWS]
                      float* __restrict__ pctx)               // [16][BAT][1024]
{
  int b_ = blockIdx.x;   // 0..31
  int sch = blockIdx.y;  // 0..7
  int t = threadIdx.x;
  int d8 = t & 127;
  int sr = t >> 7;
  float acc[8];
#pragma unroll
  for (int j = 0; j < 8; ++j) acc[j] = 0.f;
  int s0 = sch * 256;
  for (int i = 0; i < 128; ++i) {
    int s_ = s0 + i * 2 + sr;
    size_t r = (size_t)s_ * BAT + b_;
    float w = scores[r];
    u16x8 v = *reinterpret_cast<const u16x8*>(Vb + r * 1024 + d8 * 8);
#pragma unroll
    for (int j = 0; j < 8; ++j) acc[j] += w * bf2f(v[j]);
  }
  float* dst = pctx + ((size_t)(sch * 2 + sr) * BAT + b_) * 1024 + d8 * 8;
#pragma unroll
  for (int j = 0; j < 8; ++j) dst[j] = acc[j];
}

// ---------------- Kernel G: final context reduce ----------------
__global__ void k_ctx_reduce(const float* __restrict__ pctx, float* __restrict__ out) {
  int i = blockIdx.x * 256 + threadIdx.x;  // 0..32767
  float s = 0.f;
#pragma unroll
  for (int c = 0; c < 16; ++c) s += pctx[(size_t)c * 32768 + i];
  out[i] = s;
}

extern "C" void kernel_launch(void* const* d_in, const int* in_sizes, int n_in,
                              void* d_out, int out_size, void* d_ws, size_t ws_size,
                              hipStream_t stream) {
  const float* query = (const float*)d_in[0];
  const float* value = (const float*)d_in[1];
  const float* Wq    = (const float*)d_in[2];
  const float* Wv    = (const float*)d_in[3];
  const float* v     = (const float*)d_in[4];
  const float* bias  = (const float*)d_in[5];
  const float* g     = (const float*)d_in[6];
  const unsigned char* mask = (const unsigned char*)d_in[7];
  float* out = (float*)d_out;

  char* ws = (char*)d_ws;
  unsigned short* Vb  = (unsigned short*)ws;                        // 128 MB
  unsigned short* Wvb = (unsigned short*)(ws + (size_t)134217728);  // 2 MB
  float* pqb    = (float*)(ws + (size_t)134217728 + 2097152);       // 128 KB
  float* nv     = pqb + 32 * 1024;                                  // 4 KB
  float* part   = nv + 1024;                                        // 4*65536*4 = 1 MB
  float* scores = part + 4 * MROWS;                                 // 256 KB
  float* pctx   = scores + MROWS;                                   // 2 MB

  k_nv<<<1, 256, 0, stream>>>(v, g, nv);
  k_pqb<<<1024, 256, 0, stream>>>(query, Wq, bias, pqb);
  k_cvt<<<2048, 256, 0, stream>>>(value, Vb, (long long)(65536LL * 1024 / 8));
  k_cvt<<<512, 256, 0, stream>>>(Wv, Wvb, (long long)(1024LL * 1024 / 8));
  k_gemm<<<1024, 512, 0, stream>>>(Vb, Wvb, pqb, nv, part);
  k_softmax<<<32, 256, 0, stream>>>(part, mask, scores, out + 32768);
  dim3 gf(32, 8);
  k_ctx<<<gf, 256, 0, stream>>>(Vb, scores, pctx);
  k_ctx_reduce<<<128, 256, 0, stream>>>(pctx, out);
}